// Round 1
// baseline (9122.839 us; speedup 1.0000x reference)
//
#include <hip/hip_runtime.h>
#include <math.h>

// =====================================================================
// fusion: out = m * sepconv5(feat, kv, kh) + (1-m) * feat
// feat [B,C,H,W], kv/kh [B,5,H,W], m [B,1,H,W]; replication pad 2.
// =====================================================================
__global__ __launch_bounds__(256) void fusion_kernel(
        const float* __restrict__ feat, const float* __restrict__ kv,
        const float* __restrict__ kh, const float* __restrict__ m,
        float* __restrict__ out, int C, int H, int W, int total) {
    int idx = blockIdx.x * 256 + threadIdx.x;
    if (idx >= total) return;
    int x = idx % W;
    int y = (idx / W) % H;
    int b = idx / (W * H * C);
    int hw = H * W;
    int pix = y * W + x;
    float mv = m[b * hw + pix];
    float kvv[5], khv[5];
#pragma unroll
    for (int i = 0; i < 5; i++) {
        kvv[i] = kv[(b * 5 + i) * hw + pix];
        khv[i] = kh[(b * 5 + i) * hw + pix];
    }
    int cx[5], cy[5];
#pragma unroll
    for (int j = 0; j < 5; j++) {
        int xx = x + j - 2; cx[j] = xx < 0 ? 0 : (xx >= W ? W - 1 : xx);
        int yy = y + j - 2; cy[j] = yy < 0 ? 0 : (yy >= H ? H - 1 : yy);
    }
    const float* fp = feat + (size_t)(idx - pix);  // base of [b][c] plane
    float s = 0.f;
#pragma unroll
    for (int i = 0; i < 5; i++) {
        const float* rp = fp + cy[i] * W;
        float h = 0.f;
#pragma unroll
        for (int j = 0; j < 5; j++) h += rp[cx[j]] * khv[j];
        s += kvv[i] * h;
    }
    float fv = feat[idx];
    out[idx] = mv * s + (1.f - mv) * fv;
}

// =====================================================================
// stride-1 "deconv" = 3x3 conv, pad 1, weights double-flipped, + ReLU.
// w layout [Cin][Cout][3][3]. Block: 4 waves x 8 co, 16x16 tile,
// thread = 4 consecutive x pixels. Cin % 8 == 0, Cout % 32 == 0.
// =====================================================================
__global__ __launch_bounds__(256) void conv_s1_kernel(
        const float* __restrict__ in, const float* __restrict__ w,
        float* __restrict__ out, int Cin, int Cout, int H, int W) {
    __shared__ float sIn[8][18][19];   // [ci][y][x], stride 19 breaks conflicts
    __shared__ float sW[8][32][12];    // [ci][co][k], padded to 12
    const int tid = threadIdx.x;
    const int wv = tid >> 6, lane = tid & 63;
    const int pr = lane >> 2, x0 = (lane & 3) << 2;
    const int ntx = W >> 4;
    const int tx0 = (blockIdx.x % ntx) << 4, ty0 = (blockIdx.x / ntx) << 4;
    const int cob = blockIdx.y << 5;
    const int b = blockIdx.z;
    const int hw = H * W;
    float acc[8][4];
#pragma unroll
    for (int i = 0; i < 8; i++)
#pragma unroll
        for (int p = 0; p < 4; p++) acc[i][p] = 0.f;

    for (int ci0 = 0; ci0 < Cin; ci0 += 8) {
        for (int i = tid; i < 8 * 18 * 18; i += 256) {
            int ci = i / 324, r = i % 324, ly = r / 18, lx = r % 18;
            int gy = ty0 + ly - 1, gx = tx0 + lx - 1;
            float v = 0.f;
            if (gy >= 0 && gy < H && gx >= 0 && gx < W)
                v = in[(size_t)(b * Cin + ci0 + ci) * hw + gy * W + gx];
            sIn[ci][ly][lx] = v;
        }
        for (int i = tid; i < 8 * 32 * 9; i += 256) {
            int ci = i / 288, r = i % 288, co = r / 9, k = r % 9;
            // flip: wk[ky][kx] = w[2-ky][2-kx]  ->  index 8-k
            sW[ci][co][k] = w[(size_t)((ci0 + ci) * Cout + cob + co) * 9 + (8 - k)];
        }
        __syncthreads();
#pragma unroll
        for (int ci = 0; ci < 8; ci++) {
            float r0[6], r1[6], r2[6];
#pragma unroll
            for (int d = 0; d < 6; d++) {
                r0[d] = sIn[ci][pr][x0 + d];
                r1[d] = sIn[ci][pr + 1][x0 + d];
                r2[d] = sIn[ci][pr + 2][x0 + d];
            }
#pragma unroll
            for (int co = 0; co < 8; co++) {
                const float* wp = &sW[ci][(wv << 3) + co][0];
                float4 wa = *(const float4*)wp;
                float4 wb = *(const float4*)(wp + 4);
                float w8 = wp[8];
#pragma unroll
                for (int p = 0; p < 4; p++) {
                    acc[co][p] += r0[p] * wa.x + r0[p + 1] * wa.y + r0[p + 2] * wa.z
                                + r1[p] * wa.w + r1[p + 1] * wb.x + r1[p + 2] * wb.y
                                + r2[p] * wb.z + r2[p + 1] * wb.w + r2[p + 2] * w8;
                }
            }
        }
        __syncthreads();
    }
    const int oy = ty0 + pr;
#pragma unroll
    for (int co = 0; co < 8; co++) {
        float* op = out + (size_t)(b * Cout + cob + (wv << 3) + co) * hw + oy * W + tx0 + x0;
#pragma unroll
        for (int p = 0; p < 4; p++) {
            float v = acc[co][p];
            op[p] = v > 0.f ? v : 0.f;
        }
    }
}

// =====================================================================
// stride-2 deconv (k=3,p=1,op=1) + ReLU. Thread computes a 2x2 output
// quad (even/odd parities) from a 2x2 input patch -> uniform 9 taps.
// out[2y+a, 2x+b] taps: i = yout+1-2y'. Weights UNflipped.
// =====================================================================
__global__ __launch_bounds__(256) void deconv_s2_kernel(
        const float* __restrict__ in, const float* __restrict__ w,
        float* __restrict__ out, int Cin, int Cout, int Hin, int Win) {
    __shared__ float sIn[8][9][9];
    __shared__ float sW[8][32][12];
    const int tid = threadIdx.x;
    const int wv = tid >> 6, lane = tid & 63;
    const int ry = lane >> 3, cx = lane & 7;
    const int Ho = Hin * 2, Wo = Win * 2;
    const int ntx = Wo >> 4;
    const int ox0 = (blockIdx.x % ntx) << 4, oy0 = (blockIdx.x / ntx) << 4;
    const int ix0 = ox0 >> 1, iy0 = oy0 >> 1;
    const int cob = blockIdx.y << 5;
    const int b = blockIdx.z;
    const int ihw = Hin * Win, ohw = Ho * Wo;
    float acc[8][4];
#pragma unroll
    for (int i = 0; i < 8; i++)
#pragma unroll
        for (int p = 0; p < 4; p++) acc[i][p] = 0.f;

    for (int ci0 = 0; ci0 < Cin; ci0 += 8) {
        for (int i = tid; i < 8 * 81; i += 256) {
            int ci = i / 81, r = i % 81, ly = r / 9, lx = r % 9;
            int gy = iy0 + ly, gx = ix0 + lx;
            float v = 0.f;
            if (gy < Hin && gx < Win)
                v = in[(size_t)(b * Cin + ci0 + ci) * ihw + gy * Win + gx];
            sIn[ci][ly][lx] = v;
        }
        for (int i = tid; i < 8 * 32 * 9; i += 256) {
            int ci = i / 288, r = i % 288, co = r / 9, k = r % 9;
            sW[ci][co][k] = w[(size_t)((ci0 + ci) * Cout + cob + co) * 9 + k];
        }
        __syncthreads();
#pragma unroll
        for (int ci = 0; ci < 8; ci++) {
            float i00 = sIn[ci][ry][cx],     i01 = sIn[ci][ry][cx + 1];
            float i10 = sIn[ci][ry + 1][cx], i11 = sIn[ci][ry + 1][cx + 1];
#pragma unroll
            for (int co = 0; co < 8; co++) {
                const float* wp = &sW[ci][(wv << 3) + co][0];
                float4 wa = *(const float4*)wp;        // w0..w3
                float4 wb = *(const float4*)(wp + 4);  // w4..w7
                float w8 = wp[8];
                acc[co][0] += i00 * wb.x;                                          // (1,1)
                acc[co][1] += i00 * wb.y + i01 * wa.w;                             // (1,2),(1,0)
                acc[co][2] += i00 * wb.w + i10 * wa.y;                             // (2,1),(0,1)
                acc[co][3] += i00 * w8 + i01 * wb.z + i10 * wa.z + i11 * wa.x;     // (2,2),(2,0),(0,2),(0,0)
            }
        }
        __syncthreads();
    }
    const int oy = oy0 + (ry << 1), ox = ox0 + (cx << 1);
#pragma unroll
    for (int co = 0; co < 8; co++) {
        float* op = out + (size_t)(b * Cout + cob + (wv << 3) + co) * ohw + oy * Wo + ox;
        float v;
        v = acc[co][0]; op[0]      = v > 0.f ? v : 0.f;
        v = acc[co][1]; op[1]      = v > 0.f ? v : 0.f;
        v = acc[co][2]; op[Wo]     = v > 0.f ? v : 0.f;
        v = acc[co][3]; op[Wo + 1] = v > 0.f ? v : 0.f;
    }
}

// =====================================================================
// Final stride-1 conv: Cin%8==0, Cout=3, tanh epilogue. 1 px/thread.
// =====================================================================
__global__ __launch_bounds__(256) void conv_s1_c3_tanh_kernel(
        const float* __restrict__ in, const float* __restrict__ w,
        float* __restrict__ out, int Cin, int H, int W) {
    __shared__ float sIn[8][18][19];
    __shared__ float sW[8][3][9];
    const int tid = threadIdx.x;
    const int r = tid >> 4, c = tid & 15;
    const int ntx = W >> 4;
    const int tx0 = (blockIdx.x % ntx) << 4, ty0 = (blockIdx.x / ntx) << 4;
    const int b = blockIdx.z;
    const int hw = H * W;
    float acc[3] = {0.f, 0.f, 0.f};
    for (int ci0 = 0; ci0 < Cin; ci0 += 8) {
        for (int i = tid; i < 8 * 18 * 18; i += 256) {
            int ci = i / 324, rr = i % 324, ly = rr / 18, lx = rr % 18;
            int gy = ty0 + ly - 1, gx = tx0 + lx - 1;
            float v = 0.f;
            if (gy >= 0 && gy < H && gx >= 0 && gx < W)
                v = in[(size_t)(b * Cin + ci0 + ci) * hw + gy * W + gx];
            sIn[ci][ly][lx] = v;
        }
        for (int i = tid; i < 8 * 3 * 9; i += 256) {
            int ci = i / 27, rr = i % 27, co = rr / 9, k = rr % 9;
            sW[ci][co][k] = w[(size_t)((ci0 + ci) * 3 + co) * 9 + (8 - k)];
        }
        __syncthreads();
#pragma unroll
        for (int ci = 0; ci < 8; ci++) {
            float v00 = sIn[ci][r][c],     v01 = sIn[ci][r][c + 1],     v02 = sIn[ci][r][c + 2];
            float v10 = sIn[ci][r + 1][c], v11 = sIn[ci][r + 1][c + 1], v12 = sIn[ci][r + 1][c + 2];
            float v20 = sIn[ci][r + 2][c], v21 = sIn[ci][r + 2][c + 1], v22 = sIn[ci][r + 2][c + 2];
#pragma unroll
            for (int co = 0; co < 3; co++) {
                const float* wp = &sW[ci][co][0];
                acc[co] += v00 * wp[0] + v01 * wp[1] + v02 * wp[2]
                         + v10 * wp[3] + v11 * wp[4] + v12 * wp[5]
                         + v20 * wp[6] + v21 * wp[7] + v22 * wp[8];
            }
        }
        __syncthreads();
    }
#pragma unroll
    for (int co = 0; co < 3; co++)
        out[(size_t)(b * 3 + co) * hw + (ty0 + r) * W + tx0 + c] = tanhf(acc[co]);
}

// =====================================================================
// Host: pipeline. d_out layout: out(1572864) | feat_8(524288) |
// feat_16(16777216) | feat_32(16777216).  ws: A = 16,777,216 floats,
// B = 8,388,608 floats (peak 100.7 MB; stages E-G batch-split in halves).
// =====================================================================
extern "C" void kernel_launch(void* const* d_in, const int* in_sizes, int n_in,
                              void* d_out, int out_size, void* d_ws, size_t ws_size,
                              hipStream_t stream) {
    const float* cont = (const float*)d_in[0];
    const float* kv0 = (const float*)d_in[1];
    const float* kh0 = (const float*)d_in[2];
    const float* m0  = (const float*)d_in[3];
    const float* kv1 = (const float*)d_in[4];
    const float* kh1 = (const float*)d_in[5];
    const float* m1  = (const float*)d_in[6];
    const float* kv2 = (const float*)d_in[7];
    const float* kh2 = (const float*)d_in[8];
    const float* m2  = (const float*)d_in[9];
    const float* kv3 = (const float*)d_in[10];
    const float* kh3 = (const float*)d_in[11];
    const float* m3  = (const float*)d_in[12];
    const float* w1  = (const float*)d_in[13];
    const float* w2  = (const float*)d_in[14];
    const float* w3  = (const float*)d_in[15];
    const float* w4  = (const float*)d_in[16];
    const float* w5  = (const float*)d_in[17];
    const float* w6  = (const float*)d_in[18];

    float* out = (float*)d_out;
    float* f8  = out + 1572864;     // [128,64,8,8]
    float* f16 = out + 2097152;     // [128,512,16,16]
    float* f32 = out + 18874368;    // [128,128,32,32]

    float* A  = (float*)d_ws;       // 16,777,216 floats
    float* Bw = A + 16777216;       //  8,388,608 floats

    // 1. feat_8 = fusion(cont_feat)
    fusion_kernel<<<2048, 256, 0, stream>>>(cont, kv0, kh0, m0, f8, 64, 8, 8, 524288);
    // 2. t16 = relu(deconv2(feat_8, w1)): 64->512, 8->16
    deconv_s2_kernel<<<dim3(1, 16, 128), 256, 0, stream>>>(f8, w1, A, 64, 512, 8, 8);
    // 3. feat_16 = fusion(t16)
    fusion_kernel<<<65536, 256, 0, stream>>>(A, kv1, kh1, m1, f16, 512, 16, 16, 16777216);
    // 4. h1 = relu(deconv1(feat_16, w2)): 512->256 @16
    conv_s1_kernel<<<dim3(1, 8, 128), 256, 0, stream>>>(f16, w2, Bw, 512, 256, 16, 16);
    // 5. t32 = relu(deconv2(h1, w3)): 256->128, 16->32
    deconv_s2_kernel<<<dim3(4, 4, 128), 256, 0, stream>>>(Bw, w3, A, 256, 128, 16, 16);
    // 6. feat_32 = fusion(t32)
    fusion_kernel<<<65536, 256, 0, stream>>>(A, kv2, kh2, m2, f32, 128, 32, 32, 16777216);
    // 7. stages E,F,G + fusion64, batch-split in halves to fit ws
    for (int h = 0; h < 2; h++) {
        size_t bo = (size_t)h * 64;
        // E: h2 = relu(deconv1(feat_32, w4)): 128->128 @32
        conv_s1_kernel<<<dim3(4, 4, 64), 256, 0, stream>>>(
            f32 + bo * 128 * 1024, w4, Bw, 128, 128, 32, 32);
        // F: h3 = relu(deconv2(h2, w5)): 128->64, 32->64
        deconv_s2_kernel<<<dim3(16, 2, 64), 256, 0, stream>>>(Bw, w5, A, 128, 64, 32, 32);
        // G: t = tanh(deconv1(h3, w6)): 64->3 @64
        conv_s1_c3_tanh_kernel<<<dim3(16, 1, 64), 256, 0, stream>>>(A, w6, Bw, 64, 64, 64);
        // out = fusion(t)
        fusion_kernel<<<3072, 256, 0, stream>>>(
            Bw, kv3 + bo * 5 * 4096, kh3 + bo * 5 * 4096, m3 + bo * 4096,
            out + bo * 3 * 4096, 3, 64, 64, 786432);
    }
}

// Round 2
// 4513.922 us; speedup vs baseline: 2.0210x; 2.0210x over previous
//
#include <hip/hip_runtime.h>
#include <math.h>

typedef short v8s __attribute__((ext_vector_type(8)));
typedef float v16f __attribute__((ext_vector_type(16)));

// fp32 -> bf16 (RNE), no __bf16 type dependence
__device__ inline unsigned short f2bf(float f) {
    union { float f; unsigned u; } c; c.f = f;
    unsigned r = (c.u + 0x7fffu + ((c.u >> 16) & 1u)) >> 16;
    return (unsigned short)r;
}

// =====================================================================
// fusion: out = m * sepconv5(feat, kv, kh) + (1-m) * feat   (fp32)
// =====================================================================
__global__ __launch_bounds__(256) void fusion_kernel(
        const float* __restrict__ feat, const float* __restrict__ kv,
        const float* __restrict__ kh, const float* __restrict__ m,
        float* __restrict__ out, int C, int H, int W, int total) {
    int idx = blockIdx.x * 256 + threadIdx.x;
    if (idx >= total) return;
    int x = idx % W;
    int y = (idx / W) % H;
    int b = idx / (W * H * C);
    int hw = H * W;
    int pix = y * W + x;
    float mv = m[b * hw + pix];
    float kvv[5], khv[5];
#pragma unroll
    for (int i = 0; i < 5; i++) {
        kvv[i] = kv[(b * 5 + i) * hw + pix];
        khv[i] = kh[(b * 5 + i) * hw + pix];
    }
    int cx[5], cy[5];
#pragma unroll
    for (int j = 0; j < 5; j++) {
        int xx = x + j - 2; cx[j] = xx < 0 ? 0 : (xx >= W ? W - 1 : xx);
        int yy = y + j - 2; cy[j] = yy < 0 ? 0 : (yy >= H ? H - 1 : yy);
    }
    const float* fp = feat + (size_t)(idx - pix);
    float s = 0.f;
#pragma unroll
    for (int i = 0; i < 5; i++) {
        const float* rp = fp + cy[i] * W;
        float h = 0.f;
#pragma unroll
        for (int j = 0; j < 5; j++) h += rp[cx[j]] * khv[j];
        s += kvv[i] * h;
    }
    float fv = feat[idx];
    out[idx] = mv * s + (1.f - mv) * fv;
}

// =====================================================================
// NCHW fp32 -> NHWC bf16 transpose. One block per (y, b). Dynamic LDS
// [W][C+8] ushort (pad +8 breaks write-phase bank aliasing).
// =====================================================================
__global__ __launch_bounds__(256) void nchw_to_nhwc_bf16(
        const float* __restrict__ in, unsigned short* __restrict__ out,
        int C, int H, int W, int lw, int lc2) {
    extern __shared__ unsigned short sm_t[];
    const int y = blockIdx.x, b = blockIdx.y;
    const int Cp = C + 8;
    const int tid = threadIdx.x;
    for (int i = tid; i < C * W; i += 256) {
        int x = i & (W - 1), c = i >> lw;
        float v = in[(((size_t)b * C + c) * H + y) * W + x];
        sm_t[x * Cp + c] = f2bf(v);
    }
    __syncthreads();
    const unsigned* s32 = (const unsigned*)sm_t;
    unsigned* o32 = (unsigned*)(out + (((size_t)b * H + y) * W) * C);
    const int n32 = (W * C) >> 1;
    for (int i = tid; i < n32; i += 256) {
        int x = i >> lc2;
        int c2 = i - (x << lc2);
        o32[i] = s32[x * (Cp >> 1) + c2];
    }
}

// =====================================================================
// Repack torch deconv weight [Cin][Cout][3][3] fp32 -> [9][Cout][Cin]
// bf16 with the double-flip (tap t stores source index 8-t).
// =====================================================================
__global__ __launch_bounds__(256) void repack_w_bf16(
        const float* __restrict__ w, unsigned short* __restrict__ wk,
        int Cin, int Cout) {
    int idx = blockIdx.x * 256 + threadIdx.x;
    if (idx >= Cin * Cout) return;
    int ci = idx / Cout, co = idx - ci * Cout;
    const float* src = w + (size_t)idx * 9;
#pragma unroll
    for (int k = 0; k < 9; k++)
        wk[((size_t)(8 - k) * Cout + co) * Cin + ci] = f2bf(src[k]);
}

// =====================================================================
// 3x3 conv (pad 1) as implicit GEMM on MFMA 32x32x16 bf16, + ReLU.
// X: [B,H,W,Cin] bf16(ushort). Wk: [9][Cout][Cin] bf16 (pre-flipped).
// out: [B,Cout,H,W] fp32. Block = 256 thr = 2x2 waves; block tile
// M=128 co x N=128 pix (TH rows x W cols). Wave tile 64x64 = 2x2 MFMA
// subtiles. B staged in LDS, pixel stride 40 halfwords (80 B) so b128
// reads spread over all bank groups. A-fragments read from global (L2).
// =====================================================================
template<int W, int TH, int LW>
__global__ __launch_bounds__(256) void conv3x3_mfma(
        const unsigned short* __restrict__ X,
        const unsigned short* __restrict__ Wk,
        float* __restrict__ out, int Cin, int Cout, int H) {
    constexpr int TP = (TH + 2) * (W + 2);
    __shared__ unsigned short sB[TP * 40];
    const int tid = threadIdx.x;
    const int lane = tid & 63, wv = tid >> 6;
    const int wm = wv >> 1, wn = wv & 1;
    const int y0 = blockIdx.x * TH;
    const int coB = blockIdx.y * 128 + wm * 64;
    const int b = blockIdx.z;
    const int n = lane & 31, kg = lane >> 5;
    const int p0 = wn * 64 + n, p1 = p0 + 32;
    const int r0 = p0 >> LW, c0 = p0 & (W - 1);
    const int r1 = p1 >> LW, c1 = p1 & (W - 1);
    const int bo0 = (r0 * (W + 2) + c0) * 40 + kg * 8;
    const int bo1 = (r1 * (W + 2) + c1) * 40 + kg * 8;
    v16f acc00 = {}, acc01 = {}, acc10 = {}, acc11 = {};
    const size_t CoutCin = (size_t)Cout * Cin;
    const unsigned short* Abase = Wk + (size_t)(coB + n) * Cin + kg * 8;
    const unsigned short* Xb = X + (size_t)b * H * W * Cin;

    for (int ci0 = 0; ci0 < Cin; ci0 += 32) {
        for (int i = tid; i < TP * 4; i += 256) {
            int pix = i >> 2, part = i & 3;
            int py = pix / (W + 2), px = pix - py * (W + 2);
            int gy = y0 + py - 1, gx = px - 1;
            uint4 v = make_uint4(0u, 0u, 0u, 0u);
            if (gy >= 0 && gy < H && (unsigned)gx < (unsigned)W)
                v = *(const uint4*)(Xb + ((size_t)(gy * W + gx)) * Cin + ci0 + part * 8);
            *(uint4*)(sB + pix * 40 + part * 8) = v;
        }
        __syncthreads();
#pragma unroll
        for (int t = 0; t < 9; t++) {
            const int ky = t / 3, kx = t - ky * 3;
            const int toff = (ky * (W + 2) + kx) * 40;
#pragma unroll
            for (int kh = 0; kh < 2; kh++) {
                const unsigned short* ap = Abase + (size_t)t * CoutCin + ci0 + kh * 16;
                v8s A0 = *(const v8s*)(ap);
                v8s A1 = *(const v8s*)(ap + 32 * (size_t)Cin);
                v8s B0 = *(const v8s*)(sB + bo0 + toff + kh * 16);
                v8s B1 = *(const v8s*)(sB + bo1 + toff + kh * 16);
                acc00 = __builtin_amdgcn_mfma_f32_32x32x16_bf16(A0, B0, acc00, 0, 0, 0);
                acc01 = __builtin_amdgcn_mfma_f32_32x32x16_bf16(A0, B1, acc01, 0, 0, 0);
                acc10 = __builtin_amdgcn_mfma_f32_32x32x16_bf16(A1, B0, acc10, 0, 0, 0);
                acc11 = __builtin_amdgcn_mfma_f32_32x32x16_bf16(A1, B1, acc11, 0, 0, 0);
            }
        }
        __syncthreads();
    }
    // epilogue: C/D layout col=lane&31, row=(r&3)+8*(r>>2)+4*(lane>>5)
    const int hw = H * W;
#pragma unroll
    for (int sm = 0; sm < 2; sm++) {
        v16f a0 = sm ? acc10 : acc00;
        v16f a1 = sm ? acc11 : acc01;
        int cobase = coB + sm * 32 + 4 * kg;
#pragma unroll
        for (int r = 0; r < 16; r++) {
            int co = cobase + (r & 3) + 8 * (r >> 2);
            float* op = out + ((size_t)(b * Cout + co)) * hw;
            float v0 = a0[r]; v0 = v0 > 0.f ? v0 : 0.f;
            op[(y0 + r0) * W + c0] = v0;
            float v1 = a1[r]; v1 = v1 > 0.f ? v1 : 0.f;
            op[(y0 + r1) * W + c1] = v1;
        }
    }
}

// =====================================================================
// stride-2 deconv (k=3,p=1,op=1) + ReLU, fp32 (unchanged round-0)
// =====================================================================
__global__ __launch_bounds__(256) void deconv_s2_kernel(
        const float* __restrict__ in, const float* __restrict__ w,
        float* __restrict__ out, int Cin, int Cout, int Hin, int Win) {
    __shared__ float sIn[8][9][9];
    __shared__ float sW[8][32][12];
    const int tid = threadIdx.x;
    const int wv = tid >> 6, lane = tid & 63;
    const int ry = lane >> 3, cx = lane & 7;
    const int Ho = Hin * 2, Wo = Win * 2;
    const int ntx = Wo >> 4;
    const int ox0 = (blockIdx.x % ntx) << 4, oy0 = (blockIdx.x / ntx) << 4;
    const int ix0 = ox0 >> 1, iy0 = oy0 >> 1;
    const int cob = blockIdx.y << 5;
    const int b = blockIdx.z;
    const int ihw = Hin * Win, ohw = Ho * Wo;
    float acc[8][4];
#pragma unroll
    for (int i = 0; i < 8; i++)
#pragma unroll
        for (int p = 0; p < 4; p++) acc[i][p] = 0.f;

    for (int ci0 = 0; ci0 < Cin; ci0 += 8) {
        for (int i = tid; i < 8 * 81; i += 256) {
            int ci = i / 81, r = i % 81, ly = r / 9, lx = r % 9;
            int gy = iy0 + ly, gx = ix0 + lx;
            float v = 0.f;
            if (gy < Hin && gx < Win)
                v = in[(size_t)(b * Cin + ci0 + ci) * ihw + gy * Win + gx];
            sIn[ci][ly][lx] = v;
        }
        for (int i = tid; i < 8 * 32 * 9; i += 256) {
            int ci = i / 288, r = i % 288, co = r / 9, k = r % 9;
            sW[ci][co][k] = w[(size_t)((ci0 + ci) * Cout + cob + co) * 9 + k];
        }
        __syncthreads();
#pragma unroll
        for (int ci = 0; ci < 8; ci++) {
            float i00 = sIn[ci][ry][cx],     i01 = sIn[ci][ry][cx + 1];
            float i10 = sIn[ci][ry + 1][cx], i11 = sIn[ci][ry + 1][cx + 1];
#pragma unroll
            for (int co = 0; co < 8; co++) {
                const float* wp = &sW[ci][(wv << 3) + co][0];
                float4 wa = *(const float4*)wp;
                float4 wb = *(const float4*)(wp + 4);
                float w8 = wp[8];
                acc[co][0] += i00 * wb.x;
                acc[co][1] += i00 * wb.y + i01 * wa.w;
                acc[co][2] += i00 * wb.w + i10 * wa.y;
                acc[co][3] += i00 * w8 + i01 * wb.z + i10 * wa.z + i11 * wa.x;
            }
        }
        __syncthreads();
    }
    const int oy = oy0 + (ry << 1), ox = ox0 + (cx << 1);
#pragma unroll
    for (int co = 0; co < 8; co++) {
        float* op = out + (size_t)(b * Cout + cob + (wv << 3) + co) * ohw + oy * Wo + ox;
        float v;
        v = acc[co][0]; op[0]      = v > 0.f ? v : 0.f;
        v = acc[co][1]; op[1]      = v > 0.f ? v : 0.f;
        v = acc[co][2]; op[Wo]     = v > 0.f ? v : 0.f;
        v = acc[co][3]; op[Wo + 1] = v > 0.f ? v : 0.f;
    }
}

// =====================================================================
// Final stride-1 conv: Cout=3, tanh epilogue, fp32 (unchanged round-0)
// =====================================================================
__global__ __launch_bounds__(256) void conv_s1_c3_tanh_kernel(
        const float* __restrict__ in, const float* __restrict__ w,
        float* __restrict__ out, int Cin, int H, int W) {
    __shared__ float sIn[8][18][19];
    __shared__ float sW[8][3][9];
    const int tid = threadIdx.x;
    const int r = tid >> 4, c = tid & 15;
    const int ntx = W >> 4;
    const int tx0 = (blockIdx.x % ntx) << 4, ty0 = (blockIdx.x / ntx) << 4;
    const int b = blockIdx.z;
    const int hw = H * W;
    float acc[3] = {0.f, 0.f, 0.f};
    for (int ci0 = 0; ci0 < Cin; ci0 += 8) {
        for (int i = tid; i < 8 * 18 * 18; i += 256) {
            int ci = i / 324, rr = i % 324, ly = rr / 18, lx = rr % 18;
            int gy = ty0 + ly - 1, gx = tx0 + lx - 1;
            float v = 0.f;
            if (gy >= 0 && gy < H && gx >= 0 && gx < W)
                v = in[(size_t)(b * Cin + ci0 + ci) * hw + gy * W + gx];
            sIn[ci][ly][lx] = v;
        }
        for (int i = tid; i < 8 * 3 * 9; i += 256) {
            int ci = i / 27, rr = i % 27, co = rr / 9, k = rr % 9;
            sW[ci][co][k] = w[(size_t)((ci0 + ci) * 3 + co) * 9 + (8 - k)];
        }
        __syncthreads();
#pragma unroll
        for (int ci = 0; ci < 8; ci++) {
            float v00 = sIn[ci][r][c],     v01 = sIn[ci][r][c + 1],     v02 = sIn[ci][r][c + 2];
            float v10 = sIn[ci][r + 1][c], v11 = sIn[ci][r + 1][c + 1], v12 = sIn[ci][r + 1][c + 2];
            float v20 = sIn[ci][r + 2][c], v21 = sIn[ci][r + 2][c + 1], v22 = sIn[ci][r + 2][c + 2];
#pragma unroll
            for (int co = 0; co < 3; co++) {
                const float* wp = &sW[ci][co][0];
                acc[co] += v00 * wp[0] + v01 * wp[1] + v02 * wp[2]
                         + v10 * wp[3] + v11 * wp[4] + v12 * wp[5]
                         + v20 * wp[6] + v21 * wp[7] + v22 * wp[8];
            }
        }
        __syncthreads();
    }
#pragma unroll
    for (int co = 0; co < 3; co++)
        out[(size_t)(b * 3 + co) * hw + (ty0 + r) * W + tx0 + c] = tanhf(acc[co]);
}

// =====================================================================
// Host pipeline.
// d_out: out(1572864) | feat_8(524288) | feat_16(16777216) | feat_32(16777216)
// ws (<= 100,663,296 B proven):
//  phase1: A0 fp32 [0,67.1M) ; then X16 bf16 [0,33.5M), Wk2 [33.5M,35.9M),
//          h1 fp32 [67.1M,100.7M) ; then A1 fp32 [0,67.1M)
//  phase2: Wk4 [0,0.3M), X32q [0.5M,8.9M), h2q [8.9M,25.7M),
//          h3q [25.7M,59.2M), tq [59.2M,60.8M)  -- batch quarters
// =====================================================================
extern "C" void kernel_launch(void* const* d_in, const int* in_sizes, int n_in,
                              void* d_out, int out_size, void* d_ws, size_t ws_size,
                              hipStream_t stream) {
    const float* cont = (const float*)d_in[0];
    const float* kv0 = (const float*)d_in[1];
    const float* kh0 = (const float*)d_in[2];
    const float* m0  = (const float*)d_in[3];
    const float* kv1 = (const float*)d_in[4];
    const float* kh1 = (const float*)d_in[5];
    const float* m1  = (const float*)d_in[6];
    const float* kv2 = (const float*)d_in[7];
    const float* kh2 = (const float*)d_in[8];
    const float* m2  = (const float*)d_in[9];
    const float* kv3 = (const float*)d_in[10];
    const float* kh3 = (const float*)d_in[11];
    const float* m3  = (const float*)d_in[12];
    const float* w1  = (const float*)d_in[13];
    const float* w2  = (const float*)d_in[14];
    const float* w3  = (const float*)d_in[15];
    const float* w4  = (const float*)d_in[16];
    const float* w5  = (const float*)d_in[17];
    const float* w6  = (const float*)d_in[18];

    float* out = (float*)d_out;
    float* f8  = out + 1572864;     // [128,64,8,8]
    float* f16 = out + 2097152;     // [128,512,16,16]
    float* f32 = out + 18874368;    // [128,128,32,32]

    char* ws = (char*)d_ws;

    // ---- phase 1 ----
    float* A0 = (float*)ws;                                   // 67.1 MB
    fusion_kernel<<<2048, 256, 0, stream>>>(cont, kv0, kh0, m0, f8, 64, 8, 8, 524288);
    deconv_s2_kernel<<<dim3(1, 16, 128), 256, 0, stream>>>(f8, w1, A0, 64, 512, 8, 8);
    fusion_kernel<<<65536, 256, 0, stream>>>(A0, kv1, kh1, m1, f16, 512, 16, 16, 16777216);

    unsigned short* X16 = (unsigned short*)ws;                // [0, 33.5M)
    unsigned short* Wk2 = (unsigned short*)(ws + 33554432);   // 2.36 MB
    float* h1 = (float*)(ws + 67108864);                      // [67.1M, 100.7M)
    nchw_to_nhwc_bf16<<<dim3(16, 128), 256, 16 * 520 * 2, stream>>>(
        f16, X16, 512, 16, 16, 4, 8);
    repack_w_bf16<<<512, 256, 0, stream>>>(w2, Wk2, 512, 256);
    conv3x3_mfma<16, 8, 4><<<dim3(2, 2, 128), 256, 0, stream>>>(
        X16, Wk2, h1, 512, 256, 16);

    float* A1 = (float*)ws;                                   // [0, 67.1M)
    deconv_s2_kernel<<<dim3(4, 4, 128), 256, 0, stream>>>(h1, w3, A1, 256, 128, 16, 16);
    fusion_kernel<<<65536, 256, 0, stream>>>(A1, kv2, kh2, m2, f32, 128, 32, 32, 16777216);

    // ---- phase 2: batch quarters ----
    unsigned short* Wk4  = (unsigned short*)ws;               // [0, 0.3M)
    unsigned short* X32q = (unsigned short*)(ws + 524288);    // 8.4 MB
    float* h2q = (float*)(ws + 8912896);                      // 16.8 MB
    float* h3q = (float*)(ws + 25690112);                     // 33.5 MB
    float* tq  = (float*)(ws + 59244544);                     // 1.6 MB
    repack_w_bf16<<<64, 256, 0, stream>>>(w4, Wk4, 128, 128);
    for (int q = 0; q < 4; q++) {
        size_t bo = (size_t)q * 32;
        const float* f32q = f32 + bo * 128 * 1024;
        nchw_to_nhwc_bf16<<<dim3(32, 32), 256, 32 * 136 * 2, stream>>>(
            f32q, X32q, 128, 32, 32, 5, 6);
        conv3x3_mfma<32, 4, 5><<<dim3(8, 1, 32), 256, 0, stream>>>(
            X32q, Wk4, h2q, 128, 128, 32);
        deconv_s2_kernel<<<dim3(16, 2, 32), 256, 0, stream>>>(h2q, w5, h3q, 128, 64, 32, 32);
        conv_s1_c3_tanh_kernel<<<dim3(16, 1, 32), 256, 0, stream>>>(h3q, w6, tq, 64, 64, 64);
        fusion_kernel<<<1536, 256, 0, stream>>>(
            tq, kv3 + bo * 5 * 4096, kh3 + bo * 5 * 4096, m3 + bo * 4096,
            out + bo * 3 * 4096, 3, 64, 64, 393216);
    }
}

// Round 3
// 1194.650 us; speedup vs baseline: 7.6364x; 3.7784x over previous
//
#include <hip/hip_runtime.h>
#include <math.h>

typedef short v8s __attribute__((ext_vector_type(8)));
typedef float v16f __attribute__((ext_vector_type(16)));

// fp32 -> bf16 (RNE)
__device__ inline unsigned short f2bf(float f) {
    union { float f; unsigned u; } c; c.f = f;
    unsigned r = (c.u + 0x7fffu + ((c.u >> 16) & 1u)) >> 16;
    return (unsigned short)r;
}

// =====================================================================
// fusion: out = m * sepconv5(feat, kv, kh) + (1-m) * feat   (fp32)
// =====================================================================
__global__ __launch_bounds__(256) void fusion_kernel(
        const float* __restrict__ feat, const float* __restrict__ kv,
        const float* __restrict__ kh, const float* __restrict__ m,
        float* __restrict__ out, int C, int H, int W, int total) {
    int idx = blockIdx.x * 256 + threadIdx.x;
    if (idx >= total) return;
    int x = idx % W;
    int y = (idx / W) % H;
    int b = idx / (W * H * C);
    int hw = H * W;
    int pix = y * W + x;
    float mv = m[b * hw + pix];
    float kvv[5], khv[5];
#pragma unroll
    for (int i = 0; i < 5; i++) {
        kvv[i] = kv[(b * 5 + i) * hw + pix];
        khv[i] = kh[(b * 5 + i) * hw + pix];
    }
    int cx[5], cy[5];
#pragma unroll
    for (int j = 0; j < 5; j++) {
        int xx = x + j - 2; cx[j] = xx < 0 ? 0 : (xx >= W ? W - 1 : xx);
        int yy = y + j - 2; cy[j] = yy < 0 ? 0 : (yy >= H ? H - 1 : yy);
    }
    const float* fp = feat + (size_t)(idx - pix);
    float s = 0.f;
#pragma unroll
    for (int i = 0; i < 5; i++) {
        const float* rp = fp + cy[i] * W;
        float h = 0.f;
#pragma unroll
        for (int j = 0; j < 5; j++) h += rp[cx[j]] * khv[j];
        s += kvv[i] * h;
    }
    float fv = feat[idx];
    out[idx] = mv * s + (1.f - mv) * fv;
}

// =====================================================================
// NCHW fp32 -> NHWC bf16 transpose. One block per (y, b).
// =====================================================================
__global__ __launch_bounds__(256) void nchw_to_nhwc_bf16(
        const float* __restrict__ in, unsigned short* __restrict__ out,
        int C, int H, int W, int lw, int lc2) {
    extern __shared__ unsigned short sm_t[];
    const int y = blockIdx.x, b = blockIdx.y;
    const int Cp = C + 8;
    const int tid = threadIdx.x;
    for (int i = tid; i < C * W; i += 256) {
        int x = i & (W - 1), c = i >> lw;
        float v = in[(((size_t)b * C + c) * H + y) * W + x];
        sm_t[x * Cp + c] = f2bf(v);
    }
    __syncthreads();
    const unsigned* s32 = (const unsigned*)sm_t;
    unsigned* o32 = (unsigned*)(out + (((size_t)b * H + y) * W) * C);
    const int n32 = (W * C) >> 1;
    for (int i = tid; i < n32; i += 256) {
        int x = i >> lc2;
        int c2 = i - (x << lc2);
        o32[i] = s32[x * (Cp >> 1) + c2];
    }
}

// =====================================================================
// Repack [Cin][Cout][3][3] fp32 -> [9][Cout][Cin] bf16.
// flip=1: tap t stores source index 8-t (for deconv-as-conv, stride 1).
// flip=0: direct (for stride-2 deconv parity taps).
// =====================================================================
__global__ __launch_bounds__(256) void repack_w_bf16(
        const float* __restrict__ w, unsigned short* __restrict__ wk,
        int Cin, int Cout, int flip) {
    int idx = blockIdx.x * 256 + threadIdx.x;
    if (idx >= Cin * Cout) return;
    int ci = idx / Cout, co = idx - ci * Cout;
    const float* src = w + (size_t)idx * 9;
#pragma unroll
    for (int k = 0; k < 9; k++) {
        int t = flip ? (8 - k) : k;
        wk[((size_t)t * Cout + co) * Cin + ci] = f2bf(src[k]);
    }
}

// =====================================================================
// 3x3 conv (pad 1, pre-flipped weights) MFMA implicit GEMM + ReLU.
// X: [B,H,W,Cin] bf16. Wk: [9][Cout][Cin] bf16. out: [B,H,W,Cout] bf16.
// Block = 4 waves (2x2); tile M=128 co x N=128 px. Wave 64x64.
// =====================================================================
template<int W, int TH, int LW>
__global__ __launch_bounds__(256) void conv3x3_mfma(
        const unsigned short* __restrict__ X,
        const unsigned short* __restrict__ Wk,
        unsigned short* __restrict__ out, int Cin, int Cout, int H) {
    constexpr int TP = (TH + 2) * (W + 2);
    __shared__ unsigned short sB[TP * 40];
    const int tid = threadIdx.x;
    const int lane = tid & 63, wv = tid >> 6;
    const int wm = wv >> 1, wn = wv & 1;
    const int y0 = blockIdx.x * TH;
    const int coB = blockIdx.y * 128 + wm * 64;
    const int b = blockIdx.z;
    const int n = lane & 31, kg = lane >> 5;
    const int p0 = wn * 64 + n, p1 = p0 + 32;
    const int r0 = p0 >> LW, c0 = p0 & (W - 1);
    const int r1 = p1 >> LW, c1 = p1 & (W - 1);
    const int bo0 = (r0 * (W + 2) + c0) * 40 + kg * 8;
    const int bo1 = (r1 * (W + 2) + c1) * 40 + kg * 8;
    v16f acc00 = {}, acc01 = {}, acc10 = {}, acc11 = {};
    const size_t CoutCin = (size_t)Cout * Cin;
    const unsigned short* Abase = Wk + (size_t)(coB + n) * Cin + kg * 8;
    const unsigned short* Xb = X + (size_t)b * H * W * Cin;

    for (int ci0 = 0; ci0 < Cin; ci0 += 32) {
        for (int i = tid; i < TP * 4; i += 256) {
            int pix = i >> 2, part = i & 3;
            int py = pix / (W + 2), px = pix - py * (W + 2);
            int gy = y0 + py - 1, gx = px - 1;
            uint4 v = make_uint4(0u, 0u, 0u, 0u);
            if (gy >= 0 && gy < H && (unsigned)gx < (unsigned)W)
                v = *(const uint4*)(Xb + ((size_t)(gy * W + gx)) * Cin + ci0 + part * 8);
            *(uint4*)(sB + pix * 40 + part * 8) = v;
        }
        __syncthreads();
#pragma unroll
        for (int t = 0; t < 9; t++) {
            const int ky = t / 3, kx = t - ky * 3;
            const int toff = (ky * (W + 2) + kx) * 40;
#pragma unroll
            for (int kh = 0; kh < 2; kh++) {
                const unsigned short* ap = Abase + (size_t)t * CoutCin + ci0 + kh * 16;
                v8s A0 = *(const v8s*)(ap);
                v8s A1 = *(const v8s*)(ap + 32 * (size_t)Cin);
                v8s B0 = *(const v8s*)(sB + bo0 + toff + kh * 16);
                v8s B1 = *(const v8s*)(sB + bo1 + toff + kh * 16);
                acc00 = __builtin_amdgcn_mfma_f32_32x32x16_bf16(A0, B0, acc00, 0, 0, 0);
                acc01 = __builtin_amdgcn_mfma_f32_32x32x16_bf16(A0, B1, acc01, 0, 0, 0);
                acc10 = __builtin_amdgcn_mfma_f32_32x32x16_bf16(A1, B0, acc10, 0, 0, 0);
                acc11 = __builtin_amdgcn_mfma_f32_32x32x16_bf16(A1, B1, acc11, 0, 0, 0);
            }
        }
        __syncthreads();
    }
    // C/D: col=lane&31 -> pixel, row r -> co = base + (r&3) + 8*(r>>2) + 4*kg
    unsigned short* ob = out + (size_t)b * H * W * Cout;
#pragma unroll
    for (int sm = 0; sm < 2; sm++) {
        v16f a0 = sm ? acc10 : acc00;
        v16f a1 = sm ? acc11 : acc01;
        const int cobase = coB + sm * 32 + 4 * kg;
        unsigned short* q0p = ob + ((size_t)((y0 + r0) * W + c0)) * Cout + cobase;
        unsigned short* q1p = ob + ((size_t)((y0 + r1) * W + c1)) * Cout + cobase;
#pragma unroll
        for (int r2 = 0; r2 < 4; r2++) {
            ushort4 q0, q1; float v;
            v = a0[4 * r2 + 0]; v = v > 0.f ? v : 0.f; q0.x = f2bf(v);
            v = a0[4 * r2 + 1]; v = v > 0.f ? v : 0.f; q0.y = f2bf(v);
            v = a0[4 * r2 + 2]; v = v > 0.f ? v : 0.f; q0.z = f2bf(v);
            v = a0[4 * r2 + 3]; v = v > 0.f ? v : 0.f; q0.w = f2bf(v);
            *(ushort4*)(q0p + 8 * r2) = q0;
            v = a1[4 * r2 + 0]; v = v > 0.f ? v : 0.f; q1.x = f2bf(v);
            v = a1[4 * r2 + 1]; v = v > 0.f ? v : 0.f; q1.y = f2bf(v);
            v = a1[4 * r2 + 2]; v = v > 0.f ? v : 0.f; q1.z = f2bf(v);
            v = a1[4 * r2 + 3]; v = v > 0.f ? v : 0.f; q1.w = f2bf(v);
            *(ushort4*)(q1p + 8 * r2) = q1;
        }
    }
}

// =====================================================================
// stride-2 deconv (k=3,p=1,op=1) as 4 parity convs on MFMA + ReLU.
// out(2Y+py, 2X+px): ky set = {1} if py==0 else {2 (dy=0), 0 (dy=1)}.
// X: [B,Hin,W,Cin] NHWC bf16. Wk: [9][Cout][Cin] bf16 UNflipped.
// out: [B,Cout,2Hin,2W] fp32 NCHW. Block = NWM*NWN waves; wave:
// M=64 co, N=32 px strip (TH rows x W), 4 parities (8 v16f accs).
// =====================================================================
template<int W, int TH, int NWN, int NWM, int LW>
__global__ __launch_bounds__(256) void deconv2_mfma(
        const unsigned short* __restrict__ X,
        const unsigned short* __restrict__ Wk,
        float* __restrict__ out, int Cin, int Cout, int Hin) {
    constexpr int ROWS = NWN * TH + 1;
    constexpr int NPIX = ROWS * (W + 1);
    __shared__ unsigned short sB[NPIX * 40];
    const int tid = threadIdx.x;
    const int lane = tid & 63, wv = tid >> 6;
    const int wm = wv / NWN, wn = wv % NWN;
    const int n = lane & 31, kg = lane >> 5;
    const int y0 = blockIdx.x * (NWN * TH);
    const int coB = (blockIdx.y * NWM + wm) * 64;
    const int b = blockIdx.z;
    const int Yl = wn * TH + (n >> LW);
    const int Xl = n & (W - 1);
    v16f zero = {};
    v16f acc[2][2][2];
#pragma unroll
    for (int i = 0; i < 2; i++)
#pragma unroll
        for (int j = 0; j < 2; j++)
#pragma unroll
            for (int s = 0; s < 2; s++) acc[i][j][s] = zero;
    const unsigned short* Xb = X + (size_t)b * Hin * W * Cin;
    const size_t CoutCin = (size_t)Cout * Cin;
    const int PY[3] = {1, 0, 1}, DY[3] = {1, 0, 0};

    for (int ci0 = 0; ci0 < Cin; ci0 += 32) {
        for (int i = tid; i < NPIX * 4; i += 256) {
            int pix = i >> 2, part = i & 3;
            int py_ = pix / (W + 1), px_ = pix - py_ * (W + 1);
            int gy = y0 + py_, gx = px_;
            uint4 v = make_uint4(0u, 0u, 0u, 0u);
            if (gy < Hin && gx < W)
                v = *(const uint4*)(Xb + ((size_t)(gy * W + gx)) * Cin + ci0 + part * 8);
            *(uint4*)(sB + pix * 40 + part * 8) = v;
        }
        __syncthreads();
#pragma unroll
        for (int ky = 0; ky < 3; ky++) {
#pragma unroll
            for (int kx = 0; kx < 3; kx++) {
                const int py = PY[ky], dy = DY[ky];
                const int px = PY[kx], dx = DY[kx];
                const int t = ky * 3 + kx;
                const int boff = ((Yl + dy) * (W + 1) + (Xl + dx)) * 40 + kg * 8;
                const unsigned short* ap =
                    Wk + (size_t)t * CoutCin + (size_t)(coB + n) * Cin + ci0 + kg * 8;
#pragma unroll
                for (int kh = 0; kh < 2; kh++) {
                    v8s B  = *(const v8s*)(sB + boff + kh * 16);
                    v8s A0 = *(const v8s*)(ap + kh * 16);
                    v8s A1 = *(const v8s*)(ap + 32 * (size_t)Cin + kh * 16);
                    acc[py][px][0] = __builtin_amdgcn_mfma_f32_32x32x16_bf16(A0, B, acc[py][px][0], 0, 0, 0);
                    acc[py][px][1] = __builtin_amdgcn_mfma_f32_32x32x16_bf16(A1, B, acc[py][px][1], 0, 0, 0);
                }
            }
        }
        __syncthreads();
    }
    // epilogue: parity pair (px=0,1) -> consecutive ox -> float2 store
    const int Wo = 2 * W, Ho = 2 * Hin;
    const int yin = y0 + Yl;
#pragma unroll
    for (int py = 0; py < 2; py++) {
        const int oy = 2 * yin + py;
#pragma unroll
        for (int sm = 0; sm < 2; sm++) {
            const int cobase = coB + sm * 32 + 4 * kg;
#pragma unroll
            for (int r = 0; r < 16; r++) {
                int co = cobase + (r & 3) + 8 * (r >> 2);
                float v0 = acc[py][0][sm][r]; v0 = v0 > 0.f ? v0 : 0.f;
                float v1 = acc[py][1][sm][r]; v1 = v1 > 0.f ? v1 : 0.f;
                *(float2*)(out + (((size_t)(b * Cout + co) * Ho + oy) * Wo + 2 * Xl)) =
                    make_float2(v0, v1);
            }
        }
    }
}

// =====================================================================
// Final stride-1 conv: Cout=3, tanh epilogue, fp32
// =====================================================================
__global__ __launch_bounds__(256) void conv_s1_c3_tanh_kernel(
        const float* __restrict__ in, const float* __restrict__ w,
        float* __restrict__ out, int Cin, int H, int W) {
    __shared__ float sIn[8][18][19];
    __shared__ float sW[8][3][9];
    const int tid = threadIdx.x;
    const int r = tid >> 4, c = tid & 15;
    const int ntx = W >> 4;
    const int tx0 = (blockIdx.x % ntx) << 4, ty0 = (blockIdx.x / ntx) << 4;
    const int b = blockIdx.z;
    const int hw = H * W;
    float acc[3] = {0.f, 0.f, 0.f};
    for (int ci0 = 0; ci0 < Cin; ci0 += 8) {
        for (int i = tid; i < 8 * 18 * 18; i += 256) {
            int ci = i / 324, rr = i % 324, ly = rr / 18, lx = rr % 18;
            int gy = ty0 + ly - 1, gx = tx0 + lx - 1;
            float v = 0.f;
            if (gy >= 0 && gy < H && gx >= 0 && gx < W)
                v = in[(size_t)(b * Cin + ci0 + ci) * hw + gy * W + gx];
            sIn[ci][ly][lx] = v;
        }
        for (int i = tid; i < 8 * 3 * 9; i += 256) {
            int ci = i / 27, rr = i % 27, co = rr / 9, k = rr % 9;
            sW[ci][co][k] = w[(size_t)((ci0 + ci) * 3 + co) * 9 + (8 - k)];
        }
        __syncthreads();
#pragma unroll
        for (int ci = 0; ci < 8; ci++) {
            float v00 = sIn[ci][r][c],     v01 = sIn[ci][r][c + 1],     v02 = sIn[ci][r][c + 2];
            float v10 = sIn[ci][r + 1][c], v11 = sIn[ci][r + 1][c + 1], v12 = sIn[ci][r + 1][c + 2];
            float v20 = sIn[ci][r + 2][c], v21 = sIn[ci][r + 2][c + 1], v22 = sIn[ci][r + 2][c + 2];
#pragma unroll
            for (int co = 0; co < 3; co++) {
                const float* wp = &sW[ci][co][0];
                acc[co] += v00 * wp[0] + v01 * wp[1] + v02 * wp[2]
                         + v10 * wp[3] + v11 * wp[4] + v12 * wp[5]
                         + v20 * wp[6] + v21 * wp[7] + v22 * wp[8];
            }
        }
        __syncthreads();
    }
#pragma unroll
    for (int co = 0; co < 3; co++)
        out[(size_t)(b * 3 + co) * hw + (ty0 + r) * W + tx0 + c] = tanhf(acc[co]);
}

// =====================================================================
// Host pipeline. d_out: out | feat_8 | feat_16 | feat_32.
// ws phase1 (bytes): A0/t16/t32 [0,67.1M) ; X8 [67.1M,68.2M) ;
//   Wk1 [68.2M,68.75M) ; X16 [0,33.5M) ; h1b [67.1M,83.9M) ;
//   Wk3 [83.9M,84.5M) ; Wk2 [84.5M,86.8M)
// ws phase2: Wk4 [0,0.3M) ; Wk5 [0.3M,0.45M) ; X32q [0.5M,8.9M) ;
//   h2b [8.9M,17.3M) ; h3q [17.3M,50.9M) ; tq [50.9M,52.4M)
// =====================================================================
extern "C" void kernel_launch(void* const* d_in, const int* in_sizes, int n_in,
                              void* d_out, int out_size, void* d_ws, size_t ws_size,
                              hipStream_t stream) {
    const float* cont = (const float*)d_in[0];
    const float* kv0 = (const float*)d_in[1];
    const float* kh0 = (const float*)d_in[2];
    const float* m0  = (const float*)d_in[3];
    const float* kv1 = (const float*)d_in[4];
    const float* kh1 = (const float*)d_in[5];
    const float* m1  = (const float*)d_in[6];
    const float* kv2 = (const float*)d_in[7];
    const float* kh2 = (const float*)d_in[8];
    const float* m2  = (const float*)d_in[9];
    const float* kv3 = (const float*)d_in[10];
    const float* kh3 = (const float*)d_in[11];
    const float* m3  = (const float*)d_in[12];
    const float* w1  = (const float*)d_in[13];
    const float* w2  = (const float*)d_in[14];
    const float* w3  = (const float*)d_in[15];
    const float* w4  = (const float*)d_in[16];
    const float* w5  = (const float*)d_in[17];
    const float* w6  = (const float*)d_in[18];

    float* out = (float*)d_out;
    float* f8  = out + 1572864;
    float* f16 = out + 2097152;
    float* f32 = out + 18874368;

    char* ws = (char*)d_ws;

    // ---- phase 1 ----
    float* A0 = (float*)ws;                                    // t16 fp32
    unsigned short* X8  = (unsigned short*)(ws + 67108864);
    unsigned short* Wk1 = (unsigned short*)(ws + 68157440);

    fusion_kernel<<<2048, 256, 0, stream>>>(cont, kv0, kh0, m0, f8, 64, 8, 8, 524288);
    nchw_to_nhwc_bf16<<<dim3(8, 128), 256, 8 * 72 * 2, stream>>>(f8, X8, 64, 8, 8, 3, 5);
    repack_w_bf16<<<128, 256, 0, stream>>>(w1, Wk1, 64, 512, 0);
    deconv2_mfma<8, 4, 2, 2, 3><<<dim3(1, 4, 128), 256, 0, stream>>>(
        X8, Wk1, A0, 64, 512, 8);
    fusion_kernel<<<65536, 256, 0, stream>>>(A0, kv1, kh1, m1, f16, 512, 16, 16, 16777216);

    unsigned short* X16 = (unsigned short*)ws;
    unsigned short* h1b = (unsigned short*)(ws + 67108864);
    unsigned short* Wk3 = (unsigned short*)(ws + 83886080);
    unsigned short* Wk2 = (unsigned short*)(ws + 84475904);
    nchw_to_nhwc_bf16<<<dim3(16, 128), 256, 16 * 520 * 2, stream>>>(
        f16, X16, 512, 16, 16, 4, 8);
    repack_w_bf16<<<512, 256, 0, stream>>>(w2, Wk2, 512, 256, 1);
    conv3x3_mfma<16, 8, 4><<<dim3(2, 2, 128), 256, 0, stream>>>(
        X16, Wk2, h1b, 512, 256, 16);
    repack_w_bf16<<<128, 256, 0, stream>>>(w3, Wk3, 256, 128, 0);
    float* t32 = (float*)ws;
    deconv2_mfma<16, 2, 2, 2, 4><<<dim3(4, 1, 128), 256, 0, stream>>>(
        h1b, Wk3, t32, 256, 128, 16);
    fusion_kernel<<<65536, 256, 0, stream>>>(t32, kv2, kh2, m2, f32, 128, 32, 32, 16777216);

    // ---- phase 2: batch quarters ----
    unsigned short* Wk4  = (unsigned short*)ws;
    unsigned short* Wk5  = (unsigned short*)(ws + 294912);
    unsigned short* X32q = (unsigned short*)(ws + 524288);
    unsigned short* h2b  = (unsigned short*)(ws + 8912896);
    float* h3q = (float*)(ws + 17301504);
    float* tq  = (float*)(ws + 50855936);
    repack_w_bf16<<<64, 256, 0, stream>>>(w4, Wk4, 128, 128, 1);
    repack_w_bf16<<<32, 256, 0, stream>>>(w5, Wk5, 128, 64, 0);
    for (int q = 0; q < 4; q++) {
        size_t bo = (size_t)q * 32;
        const float* f32q = f32 + bo * 128 * 1024;
        nchw_to_nhwc_bf16<<<dim3(32, 32), 256, 32 * 136 * 2, stream>>>(
            f32q, X32q, 128, 32, 32, 5, 6);
        conv3x3_mfma<32, 4, 5><<<dim3(8, 1, 32), 256, 0, stream>>>(
            X32q, Wk4, h2b, 128, 128, 32);
        deconv2_mfma<32, 1, 4, 1, 5><<<dim3(8, 1, 32), 256, 0, stream>>>(
            h2b, Wk5, h3q, 128, 64, 32);
        conv_s1_c3_tanh_kernel<<<dim3(16, 1, 32), 256, 0, stream>>>(h3q, w6, tq, 64, 64, 64);
        fusion_kernel<<<1536, 256, 0, stream>>>(
            tq, kv3 + bo * 5 * 4096, kh3 + bo * 5 * 4096, m3 + bo * 4096,
            out + bo * 3 * 4096, 3, 64, 64, 393216);
    }
}